// Round 1
// 169.284 us; speedup vs baseline: 1.1220x; 1.1220x over previous
//
#include <hip/hip_runtime.h>

// GCN layer: out = relu(x @ W_self^T + b_self + segment_mean(x[src], dst) @ W_neigh^T)
// N = 100000 nodes, D = 64, E = 1.25M edges.
//
// Pipeline (5 kernels):
//   x2bf_prep   : x fp32 -> bf16 (12.8 MB); last block also inits cursors and
//                 packs W_self/W_neigh to bf16 (one-time, removes per-block
//                 packing VALU from gcn_gemm).
//   bin_scatter : LDS-staged radix scatter into 98 buckets of 1024 dst-nodes;
//                 block-local int-LDS hist + scan + contiguous run claim ->
//                 full-line writes (no cross-XCD partial-line churn).
//   sb_csr      : one 1024-thread block per bucket (98 blocks). Window is read
//                 from global ONCE into registers (14 statically-unrolled
//                 entries/thread), node-sort happens entirely in LDS (57 KB
//                 staging, offset array doubles as scatter cursor), then one
//                 coalesced linear flush to col. Previous version did per-edge
//                 random 4B global writes (~80 MB effective line traffic for
//                 5 MB payload) + a second global window read.
//                 NOTE: LDS *int* atomics only — LDS fp32 atomicAdd is a CAS
//                 loop on gfx950 and serializes (r3/r11: ~500 µs disasters).
//   gcn_gather  : one wave per node on bf16 rows (128B): 8 edges per dwordx4
//                 instruction, fp32 accumulate, cross-oct shuffle reduce,
//                 mean folded into bf16 write. rowstart/rowcnt packed int2.
//   gcn_gemm    : bf16 MFMA (16x16x32), zero LDS; A-frags straight from bf16
//                 xb/aggb; B-frags from pre-packed bf16 weights; bias+relu.

#define BKSH 10               // log2(nodes per bucket)
#define BKN 1024              // nodes per bucket
#define NBMAX 128             // >= NB = 98
#define CAPE 14336            // edge capacity per bucket (mean 12800, +13 sigma)
#define WPT (CAPE / 1024)     // window entries per thread in sb_csr = 14
#define CHUNK 4096            // edges per scatter block

typedef __attribute__((ext_vector_type(8))) short short8;
typedef __attribute__((ext_vector_type(4))) float floatx4;

// fp32 -> bf16 round-to-nearest-even, branch-free.
static __device__ inline unsigned short f2bf(float f) {
  union { float f; unsigned int u; } v;
  v.f = f;
  unsigned int r = v.u + 0x7FFFu + ((v.u >> 16) & 1u);
  return (unsigned short)(r >> 16);
}

static __device__ inline short8 pack8(float4 a, float4 b) {
  short8 s;
  s[0] = (short)f2bf(a.x); s[1] = (short)f2bf(a.y);
  s[2] = (short)f2bf(a.z); s[3] = (short)f2bf(a.w);
  s[4] = (short)f2bf(b.x); s[5] = (short)f2bf(b.y);
  s[6] = (short)f2bf(b.z); s[7] = (short)f2bf(b.w);
  return s;
}

// unpack 8 bf16 (4 dwords) and accumulate into 8 fp32.
static __device__ inline void add8(float* a, short8 sv) {
  union { short8 s; unsigned int u[4]; } c; c.s = sv;
#pragma unroll
  for (int i = 0; i < 4; ++i) {
    a[2 * i]     += __uint_as_float(c.u[i] << 16);
    a[2 * i + 1] += __uint_as_float(c.u[i] & 0xFFFF0000u);
  }
}

// x fp32->bf16; last block: cursor init + one-time weight pack to bf16.
__global__ __launch_bounds__(256) void x2bf_prep(const float* __restrict__ x,
                                                 unsigned short* __restrict__ xb,
                                                 long long n,
                                                 int* __restrict__ cursor,
                                                 const float* __restrict__ Wself,
                                                 const float* __restrict__ Wneigh,
                                                 unsigned short* __restrict__ wsb,
                                                 unsigned short* __restrict__ wnb) {
  int t = threadIdx.x;
  long long i = ((long long)blockIdx.x * 256 + t) * 8;
  if (i < n) {
    float4 a = *(const float4*)&x[i];
    float4 b = *(const float4*)&x[i + 4];
    *(short8*)&xb[i] = pack8(a, b);
  }
  if (blockIdx.x == gridDim.x - 1) {
    if (t < NBMAX) cursor[t] = t * CAPE;
    // pack 2 x [64x64] fp32 weights -> bf16 (512 short8 groups each)
    for (int g = t; g < 512; g += 256) {
      const float* p = &Wself[g * 8];
      *(short8*)&wsb[g * 8] = pack8(*(const float4*)p, *(const float4*)(p + 4));
      const float* q = &Wneigh[g * 8];
      *(short8*)&wnb[g * 8] = pack8(*(const float4*)q, *(const float4*)(q + 4));
    }
  }
}

// LDS-staged radix scatter into fixed-capacity bucket regions.
__global__ __launch_bounds__(256) void bin_scatter(const int* __restrict__ src,
                                                   const int* __restrict__ dst,
                                                   int* __restrict__ cursor,
                                                   int* __restrict__ ebuf, int E, int NB) {
  __shared__ int h[NBMAX], loff[NBMAX], gbase[NBMAX];
  __shared__ int sbuf[CHUNK];
  int t = threadIdx.x;
  if (t < NBMAX) h[t] = 0;
  __syncthreads();

  int base = blockIdx.x * CHUNK;
  int myd[CHUNK / 256], mys[CHUNK / 256];
#pragma unroll
  for (int i = 0; i < CHUNK / 256; ++i) {
    int e = base + t + 256 * i;  // coalesced
    if (e < E) {
      myd[i] = dst[e];
      mys[i] = src[e];
      atomicAdd(&h[myd[i] >> BKSH], 1);
    } else myd[i] = -1;
  }
  __syncthreads();

  if (t < 64) {  // wave 0: exclusive scan of h[0..127]
    int i0 = 2 * t, i1 = 2 * t + 1;
    int v0 = h[i0], v1 = h[i1];
    int s = v0 + v1, inc = s;
#pragma unroll
    for (int off = 1; off < 64; off <<= 1) {
      int u = __shfl_up(inc, off, 64);
      if (t >= off) inc += u;
    }
    int ex = inc - s;
    loff[i0] = ex; loff[i1] = ex + v0;
  }
  __syncthreads();

  if (t < NB) {
    if (h[t] > 0) gbase[t] = atomicAdd(&cursor[t], h[t]);  // claim contiguous run
  }
  if (t < NBMAX) h[t] = 0;  // reuse as local cursor
  __syncthreads();

#pragma unroll
  for (int i = 0; i < CHUNK / 256; ++i) {
    if (myd[i] >= 0) {
      int b = myd[i] >> BKSH;
      int p = atomicAdd(&h[b], 1);           // LDS int atomic: native, fast
      sbuf[loff[b] + p] = mys[i] | ((myd[i] & (BKN - 1)) << 17);  // src < 2^17
    }
  }
  __syncthreads();

  int w = t >> 6, lane = t & 63;
  for (int b = w; b < NB; b += 4) {
    int c = h[b], lo = loff[b], go = gbase[b];
    for (int j = lane; j < c; j += 64)
      ebuf[go + j] = sbuf[lo + j];
  }
}

// One 1024-thread block per 1024-node bucket (98 blocks). Window read ONCE
// from global into registers; count -> block scan -> in-LDS node-sort ->
// coalesced flush. cnt[] doubles as scatter cursor (seeded with exclusive
// prefix), so the atomicAdd result IS the final sorted position.
__global__ __launch_bounds__(1024) void sb_csr(const int* __restrict__ cursor,
                                               const int* __restrict__ ebuf,
                                               int* __restrict__ col,
                                               int2* __restrict__ rowse, int N) {
  __shared__ int sbuf[CAPE];   // 57344 B
  __shared__ int cnt[BKN];     //  4096 B
  __shared__ int wsum[16];     // total 61504 B < 64 KB
  int b = blockIdx.x, t = threadIdx.x;
  int s = b * CAPE, e = cursor[b];
  int n = e - s;

  // stage window into registers (static indices -> stays in VGPRs)
  int my[WPT];
#pragma unroll
  for (int i = 0; i < WPT; ++i) {
    int j = s + t + (i << 10);
    my[i] = (j < e) ? ebuf[j] : -1;  // entries are < 2^27, so -1 is a safe sentinel
  }

  cnt[t] = 0;
  __syncthreads();
#pragma unroll
  for (int i = 0; i < WPT; ++i)
    if (my[i] >= 0) atomicAdd(&cnt[(my[i] >> 17) & (BKN - 1)], 1);
  __syncthreads();

  // block exclusive scan over 1024 (1 per thread, 16 waves)
  int v = cnt[t];
  int lane = t & 63, w = t >> 6;
  int inc = v;
#pragma unroll
  for (int o = 1; o < 64; o <<= 1) {
    int u = __shfl_up(inc, o, 64);
    if (lane >= o) inc += u;
  }
  if (lane == 63) wsum[w] = inc;
  __syncthreads();
  if (t < 16) {
    int s0 = wsum[t], incw = s0;
#pragma unroll
    for (int o = 1; o < 16; o <<= 1) {
      int u = __shfl_up(incw, o, 64);
      if (t >= o) incw += u;
    }
    wsum[t] = incw - s0;
  }
  __syncthreads();
  int ex = wsum[w] + inc - v;
  int node = (b << BKSH) + t;
  if (node < N) rowse[node] = make_int2(s + ex, v);
  __syncthreads();
  cnt[t] = ex;  // seed scatter cursor with exclusive prefix
  __syncthreads();

  // in-LDS node-sort: atomic result is the final position in the window
#pragma unroll
  for (int i = 0; i < WPT; ++i) {
    if (my[i] >= 0) {
      int nl = (my[i] >> 17) & (BKN - 1);
      int p = atomicAdd(&cnt[nl], 1);
      sbuf[p] = my[i] & 0x1FFFF;
    }
  }
  __syncthreads();

  // coalesced flush (was: per-edge random 4B global writes)
  for (int j = t; j < n; j += 1024) col[s + j] = sbuf[j];
}

// One wave per node on bf16 rows (128B). Oct o handles edges j = s+o, s+o+8...;
// one dwordx4 instruction covers 8 edges (1KB). fp32 accumulate, 3-round
// cross-oct shuffle reduce, bf16 agg write (mean folded).
__global__ __launch_bounds__(256) void gcn_gather(const unsigned short* __restrict__ xb,
                                                  const int2* __restrict__ rowse,
                                                  const int* __restrict__ col,
                                                  unsigned short* __restrict__ aggb,
                                                  int N) {
  int gid = blockIdx.x * 256 + threadIdx.x;
  int node = gid >> 6;
  if (node >= N) return;
  int lane = threadIdx.x & 63;
  int o = lane >> 3, d = lane & 7;
  int2 se = rowse[node];
  int s = se.x, c = se.y, e = s + c;

  float a[8] = {0.f, 0.f, 0.f, 0.f, 0.f, 0.f, 0.f, 0.f};
  float b2[8] = {0.f, 0.f, 0.f, 0.f, 0.f, 0.f, 0.f, 0.f};
  int j = s + o;
  for (; j + 8 < e; j += 16) {  // 16 edges in flight per wave
    int c0 = col[j], c1 = col[j + 8];
    short8 v0 = *(const short8*)&xb[(long long)c0 * 64 + d * 8];
    short8 v1 = *(const short8*)&xb[(long long)c1 * 64 + d * 8];
    add8(a, v0);
    add8(b2, v1);
  }
  for (; j < e; j += 8) {
    short8 v = *(const short8*)&xb[(long long)col[j] * 64 + d * 8];
    add8(a, v);
  }
#pragma unroll
  for (int k = 0; k < 8; ++k) a[k] += b2[k];

#pragma unroll
  for (int m = 8; m <= 32; m <<= 1) {
#pragma unroll
    for (int k = 0; k < 8; ++k) a[k] += __shfl_xor(a[k], m, 64);
  }

  if (o == 0) {
    float inv = 1.0f / fmaxf((float)c, 1.0f);
    short8 r;
#pragma unroll
    for (int k = 0; k < 8; ++k) r[k] = (short)f2bf(a[k] * inv);
    *(short8*)&aggb[(long long)node * 64 + d * 8] = r;  // 8 lanes x 16B = 128B
  }
}

// bf16 MFMA GEMM, zero LDS. Wave w owns nodes [blk*64 + w*16, +16).
// A-frags load DIRECTLY from bf16 arrays; B-frags from pre-packed bf16 weights.
// One accumulator: D = Ax*Ws^T + Aagg*Wn^T. C/D: col=lane&15, row=quad*4+reg.
__global__ __launch_bounds__(256) void gcn_gemm(const unsigned short* __restrict__ xb,
                                                const unsigned short* __restrict__ aggb,
                                                const unsigned short* __restrict__ wsb,
                                                const float* __restrict__ bself,
                                                const unsigned short* __restrict__ wnb,
                                                float* __restrict__ out, int N) {
  int lane = threadIdx.x & 63;
  int w = threadIdx.x >> 6;
  int tb = blockIdx.x * 64 + w * 16;
  int m = lane & 15, q = lane >> 4;

  long long rowA = (long long)min(tb + m, N - 1) * 64;
  short8 ax[2], aa[2];
#pragma unroll
  for (int ks = 0; ks < 2; ++ks) {
    ax[ks] = *(const short8*)&xb[rowA + ks * 32 + q * 8];
    aa[ks] = *(const short8*)&aggb[rowA + ks * 32 + q * 8];
  }

#pragma unroll
  for (int nt = 0; nt < 4; ++nt) {
    int ob = nt * 16;
    long long rowB = (long long)(ob + m) * 64;
    floatx4 acc = {0.f, 0.f, 0.f, 0.f};
#pragma unroll
    for (int ks = 0; ks < 2; ++ks) {
      short8 bw = *(const short8*)&wsb[rowB + ks * 32 + q * 8];
      acc = __builtin_amdgcn_mfma_f32_16x16x32_bf16(ax[ks], bw, acc, 0, 0, 0);
      short8 bn = *(const short8*)&wnb[rowB + ks * 32 + q * 8];
      acc = __builtin_amdgcn_mfma_f32_16x16x32_bf16(aa[ks], bn, acc, 0, 0, 0);
    }
    float bias = bself[ob + m];
#pragma unroll
    for (int r = 0; r < 4; ++r) {
      int node = tb + q * 4 + r;
      if (node < N) {
        float v = acc[r] + bias;
        out[(long long)node * 64 + ob + m] = fmaxf(v, 0.f);
      }
    }
  }
}

extern "C" void kernel_launch(void* const* d_in, const int* in_sizes, int n_in,
                              void* d_out, int out_size, void* d_ws, size_t ws_size,
                              hipStream_t stream) {
  const float* x      = (const float*)d_in[0];
  const int*   eidx   = (const int*)d_in[1];
  const float* Wself  = (const float*)d_in[2];
  const float* bself  = (const float*)d_in[3];
  const float* Wneigh = (const float*)d_in[4];
  float* out = (float*)d_out;

  const int N = in_sizes[0] / 64;
  const int E = in_sizes[1] / 2;
  const int* src = eidx;      // edge_index row 0
  const int* dst = eidx + E;  // edge_index row 1
  const int NB = (N + BKN - 1) / BKN;  // 98 buckets of 1024 nodes

  // ws layout: xb[N*64] bf16 | aggb[N*64] bf16 | cursor[128] | wsb[4096] bf16
  //            | wnb[4096] bf16 | rowse[N] int2 | ebuf[NB*CAPE] | col[E]
  unsigned short* xb   = (unsigned short*)d_ws;
  unsigned short* aggb = xb + (size_t)N * 64;
  int* cursor   = (int*)(aggb + (size_t)N * 64);
  unsigned short* wsb = (unsigned short*)(cursor + NBMAX);
  unsigned short* wnb = wsb + 4096;
  int2* rowse   = (int2*)(wnb + 4096);
  int* ebuf     = (int*)(rowse + N);
  int* col      = ebuf + (size_t)NB * CAPE;

  long long nx = (long long)N * 64;
  int xblocks = (int)(nx / 8 + 255) / 256 + 1;  // +1: prep block (cursor + W pack)
  x2bf_prep<<<xblocks, 256, 0, stream>>>(x, xb, nx, cursor, Wself, Wneigh, wsb, wnb);

  int cb = (E + CHUNK - 1) / CHUNK;  // 306 scatter blocks
  bin_scatter<<<cb, 256, 0, stream>>>(src, dst, cursor, ebuf, E, NB);
  sb_csr<<<NB, 1024, 0, stream>>>(cursor, ebuf, col, rowse, N);
  gcn_gather<<<(int)((nx + 255) / 256), 256, 0, stream>>>(xb, rowse, col, aggb, N);
  gcn_gemm<<<(N + 63) / 64, 256, 0, stream>>>(xb, aggb, wsb, bself, wnb, out, N);
}

// Round 2
// 168.854 us; speedup vs baseline: 1.1249x; 1.0025x over previous
//
#include <hip/hip_runtime.h>

// GCN layer: out = relu(x @ W_self^T + b_self + segment_mean(x[src], dst) @ W_neigh^T)
// N = 100000 nodes, D = 64, E = 1.25M edges.
//
// Pipeline (memset + 4 kernels):
//   memset      : cursor[256] = 0 (1 KB, capturable stream op).
//   k1_prep     : block-role split. Blocks [0,SCB): LDS-staged radix scatter of
//                 edges into 196 buckets of 512 dst-nodes (claims contiguous
//                 runs via global cursor atomics, full-line ebuf writes).
//                 Blocks [SCB, SCB+3125): x fp32 -> bf16. Last block: weights
//                 fp32 -> bf16 pack. Overlaps HBM streaming with atomic work.
//   sb_csr      : one 512-thread block per 512-node bucket (196 blocks -> 2x
//                 the CU coverage of the old 98x1024 version, half the
//                 per-block LDS-atomic critical path). Window read ONCE into
//                 registers, in-LDS node-sort, coalesced flush to col.
//                 NOTE: LDS *int* atomics only — LDS fp32 atomicAdd is a CAS
//                 loop on gfx950 and serializes (r3/r11: ~500 µs disasters).
//   gcn_gather  : one wave per node on bf16 rows (128B): 8 edges per dwordx4,
//                 ALWAYS 2 gather loads in flight (clamped 2nd index +
//                 predicated accumulate — avg degree 12.5 means the old
//                 16-edge main loop rarely ran; tail loop was 1-deep).
//   gcn_gemm    : bf16 MFMA (16x16x32), zero LDS; A-frags straight from bf16
//                 xb/aggb; B-frags from pre-packed bf16 weights; bias+relu.

#define BKSH 9                // log2(nodes per bucket)
#define BKN 512               // nodes per bucket
#define NBMAX 256             // >= NB = 196
#define CAPE 7168             // edge capacity per bucket (mean 6400, +9.6 sigma)
#define WPT (CAPE / BKN)      // window entries per thread in sb_csr = 14
#define CHUNK 8192            // edges per scatter block (keeps flush runs ~42)
#define EPT (CHUNK / 256)     // edges per thread in scatter = 32

typedef __attribute__((ext_vector_type(8))) short short8;
typedef __attribute__((ext_vector_type(4))) float floatx4;

// fp32 -> bf16 round-to-nearest-even, branch-free.
static __device__ inline unsigned short f2bf(float f) {
  union { float f; unsigned int u; } v;
  v.f = f;
  unsigned int r = v.u + 0x7FFFu + ((v.u >> 16) & 1u);
  return (unsigned short)(r >> 16);
}

static __device__ inline short8 pack8(float4 a, float4 b) {
  short8 s;
  s[0] = (short)f2bf(a.x); s[1] = (short)f2bf(a.y);
  s[2] = (short)f2bf(a.z); s[3] = (short)f2bf(a.w);
  s[4] = (short)f2bf(b.x); s[5] = (short)f2bf(b.y);
  s[6] = (short)f2bf(b.z); s[7] = (short)f2bf(b.w);
  return s;
}

// unpack 8 bf16 (4 dwords) and accumulate into 8 fp32.
static __device__ inline void add8(float* a, short8 sv) {
  union { short8 s; unsigned int u[4]; } c; c.s = sv;
#pragma unroll
  for (int i = 0; i < 4; ++i) {
    a[2 * i]     += __uint_as_float(c.u[i] << 16);
    a[2 * i + 1] += __uint_as_float(c.u[i] & 0xFFFF0000u);
  }
}

// Fused: edge radix-scatter (blocks < SCB) | x fp32->bf16 | weight pack.
__global__ __launch_bounds__(256) void k1_prep(
    const float* __restrict__ x, unsigned short* __restrict__ xb, long long n,
    const float* __restrict__ Wself, const float* __restrict__ Wneigh,
    unsigned short* __restrict__ wsb, unsigned short* __restrict__ wnb,
    const int* __restrict__ src, const int* __restrict__ dst,
    int* __restrict__ cursor, int* __restrict__ ebuf, int E, int NB, int SCB) {
  __shared__ int h[NBMAX], loff[NBMAX], gbase[NBMAX];
  __shared__ int sbuf[CHUNK];
  int t = threadIdx.x;
  int bid = blockIdx.x;

  if (bid >= SCB) {
    // ---- streaming role: x -> bf16 ----
    long long i = ((long long)(bid - SCB) * 256 + t) * 8;
    if (i < n) {
      float4 a = *(const float4*)&x[i];
      float4 b = *(const float4*)&x[i + 4];
      *(short8*)&xb[i] = pack8(a, b);
    }
    if (bid == gridDim.x - 1) {
      // one-time weight pack: 2 x [64x64] fp32 -> bf16
      for (int g = t; g < 512; g += 256) {
        const float* p = &Wself[g * 8];
        *(short8*)&wsb[g * 8] = pack8(*(const float4*)p, *(const float4*)(p + 4));
        const float* q = &Wneigh[g * 8];
        *(short8*)&wnb[g * 8] = pack8(*(const float4*)q, *(const float4*)(q + 4));
      }
    }
    return;
  }

  // ---- scatter role ----
  if (t < NBMAX) h[t] = 0;
  __syncthreads();

  int base = bid * CHUNK;
  int myd[EPT], mys[EPT];
#pragma unroll
  for (int i = 0; i < EPT; ++i) {
    int e = base + t + 256 * i;  // coalesced
    if (e < E) {
      myd[i] = dst[e];
      mys[i] = src[e];
      atomicAdd(&h[myd[i] >> BKSH], 1);
    } else myd[i] = -1;
  }
  __syncthreads();

  if (t < 64) {  // wave 0: exclusive scan of h[0..255], 4 per lane
    int i0 = 4 * t;
    int v0 = h[i0], v1 = h[i0 + 1], v2 = h[i0 + 2], v3 = h[i0 + 3];
    int s4 = v0 + v1 + v2 + v3, inc = s4;
#pragma unroll
    for (int off = 1; off < 64; off <<= 1) {
      int u = __shfl_up(inc, off, 64);
      if (t >= off) inc += u;
    }
    int ex = inc - s4;
    loff[i0] = ex; loff[i0 + 1] = ex + v0;
    loff[i0 + 2] = ex + v0 + v1; loff[i0 + 3] = ex + v0 + v1 + v2;
  }
  __syncthreads();

  if (t < NB) {
    if (h[t] > 0) gbase[t] = t * CAPE + atomicAdd(&cursor[t], h[t]);  // claim run
  }
  if (t < NBMAX) h[t] = 0;  // reuse as local cursor
  __syncthreads();

#pragma unroll
  for (int i = 0; i < EPT; ++i) {
    if (myd[i] >= 0) {
      int b = myd[i] >> BKSH;
      int p = atomicAdd(&h[b], 1);           // LDS int atomic: native, fast
      sbuf[loff[b] + p] = mys[i] | ((myd[i] & (BKN - 1)) << 17);  // src < 2^17
    }
  }
  __syncthreads();

  int w = t >> 6, lane = t & 63;
  for (int b = w; b < NB; b += 4) {
    int c = h[b], lo = loff[b], go = gbase[b];
    for (int j = lane; j < c; j += 64)
      ebuf[go + j] = sbuf[lo + j];
  }
}

// One 512-thread block per 512-node bucket (196 blocks). Window read ONCE
// from global into registers; count -> block scan -> in-LDS node-sort ->
// coalesced flush. cnt[] doubles as scatter cursor (seeded with exclusive
// prefix), so the atomicAdd result IS the final sorted position.
__global__ __launch_bounds__(512) void sb_csr(const int* __restrict__ cursor,
                                              const int* __restrict__ ebuf,
                                              int* __restrict__ col,
                                              int2* __restrict__ rowse, int N) {
  __shared__ int sbuf[CAPE];   // 28672 B
  __shared__ int cnt[BKN];     //  2048 B
  __shared__ int wsum[8];      // total ~30.8 KB
  int b = blockIdx.x, t = threadIdx.x;
  int s = b * CAPE;
  int n = cursor[b];
  int e = s + n;

  // stage window into registers (static indices -> stays in VGPRs)
  int my[WPT];
#pragma unroll
  for (int i = 0; i < WPT; ++i) {
    int j = s + t + i * BKN;
    my[i] = (j < e) ? ebuf[j] : -1;  // entries < 2^26, -1 is a safe sentinel
  }

  cnt[t] = 0;
  __syncthreads();
#pragma unroll
  for (int i = 0; i < WPT; ++i)
    if (my[i] >= 0) atomicAdd(&cnt[(my[i] >> 17) & (BKN - 1)], 1);
  __syncthreads();

  // block exclusive scan over 512 (1 per thread, 8 waves)
  int v = cnt[t];
  int lane = t & 63, w = t >> 6;
  int inc = v;
#pragma unroll
  for (int o = 1; o < 64; o <<= 1) {
    int u = __shfl_up(inc, o, 64);
    if (lane >= o) inc += u;
  }
  if (lane == 63) wsum[w] = inc;
  __syncthreads();
  if (t < 8) {
    int s0 = wsum[t], incw = s0;
#pragma unroll
    for (int o = 1; o < 8; o <<= 1) {
      int u = __shfl_up(incw, o, 64);
      if (t >= o) incw += u;
    }
    wsum[t] = incw - s0;
  }
  __syncthreads();
  int ex = wsum[w] + inc - v;
  int node = (b << BKSH) + t;
  if (node < N) rowse[node] = make_int2(s + ex, v);
  __syncthreads();
  cnt[t] = ex;  // seed scatter cursor with exclusive prefix
  __syncthreads();

  // in-LDS node-sort: atomic result is the final position in the window
#pragma unroll
  for (int i = 0; i < WPT; ++i) {
    if (my[i] >= 0) {
      int nl = (my[i] >> 17) & (BKN - 1);
      int p = atomicAdd(&cnt[nl], 1);
      sbuf[p] = my[i] & 0x1FFFF;
    }
  }
  __syncthreads();

  // coalesced flush
  for (int j = t; j < n; j += BKN) col[s + j] = sbuf[j];
}

// One wave per node on bf16 rows (128B). Oct o handles edges j = s+o, s+o+8...;
// one dwordx4 instruction covers 8 edges (1KB). Always 2 loads in flight
// (clamped 2nd index, predicated accumulate). fp32 accumulate, 3-round
// cross-oct shuffle reduce, bf16 agg write (mean folded).
__global__ __launch_bounds__(256) void gcn_gather(const unsigned short* __restrict__ xb,
                                                  const int2* __restrict__ rowse,
                                                  const int* __restrict__ col,
                                                  unsigned short* __restrict__ aggb,
                                                  int N) {
  int gid = blockIdx.x * 256 + threadIdx.x;
  int node = gid >> 6;
  if (node >= N) return;
  int lane = threadIdx.x & 63;
  int o = lane >> 3, d = lane & 7;
  int2 se = rowse[node];
  int s = se.x, c = se.y, e = s + c;

  float a[8] = {0.f, 0.f, 0.f, 0.f, 0.f, 0.f, 0.f, 0.f};
  float b2[8] = {0.f, 0.f, 0.f, 0.f, 0.f, 0.f, 0.f, 0.f};
  for (int j = s + o; j < e; j += 16) {
    int c0 = col[j];
    bool h2 = (j + 8) < e;
    int c1 = h2 ? col[j + 8] : c0;  // clamp: redundant load hits same line
    short8 v0 = *(const short8*)&xb[(long long)c0 * 64 + d * 8];
    short8 v1 = *(const short8*)&xb[(long long)c1 * 64 + d * 8];
    add8(a, v0);
    if (h2) add8(b2, v1);
  }
#pragma unroll
  for (int k = 0; k < 8; ++k) a[k] += b2[k];

#pragma unroll
  for (int m = 8; m <= 32; m <<= 1) {
#pragma unroll
    for (int k = 0; k < 8; ++k) a[k] += __shfl_xor(a[k], m, 64);
  }

  if (o == 0) {
    float inv = 1.0f / fmaxf((float)c, 1.0f);
    short8 r;
#pragma unroll
    for (int k = 0; k < 8; ++k) r[k] = (short)f2bf(a[k] * inv);
    *(short8*)&aggb[(long long)node * 64 + d * 8] = r;  // 8 lanes x 16B = 128B
  }
}

// bf16 MFMA GEMM, zero LDS. Wave w owns nodes [blk*64 + w*16, +16).
// A-frags load DIRECTLY from bf16 arrays; B-frags from pre-packed bf16 weights.
// One accumulator: D = Ax*Ws^T + Aagg*Wn^T. C/D: col=lane&15, row=quad*4+reg.
__global__ __launch_bounds__(256) void gcn_gemm(const unsigned short* __restrict__ xb,
                                                const unsigned short* __restrict__ aggb,
                                                const unsigned short* __restrict__ wsb,
                                                const float* __restrict__ bself,
                                                const unsigned short* __restrict__ wnb,
                                                float* __restrict__ out, int N) {
  int lane = threadIdx.x & 63;
  int w = threadIdx.x >> 6;
  int tb = blockIdx.x * 64 + w * 16;
  int m = lane & 15, q = lane >> 4;

  long long rowA = (long long)min(tb + m, N - 1) * 64;
  short8 ax[2], aa[2];
#pragma unroll
  for (int ks = 0; ks < 2; ++ks) {
    ax[ks] = *(const short8*)&xb[rowA + ks * 32 + q * 8];
    aa[ks] = *(const short8*)&aggb[rowA + ks * 32 + q * 8];
  }

#pragma unroll
  for (int nt = 0; nt < 4; ++nt) {
    int ob = nt * 16;
    long long rowB = (long long)(ob + m) * 64;
    floatx4 acc = {0.f, 0.f, 0.f, 0.f};
#pragma unroll
    for (int ks = 0; ks < 2; ++ks) {
      short8 bw = *(const short8*)&wsb[rowB + ks * 32 + q * 8];
      acc = __builtin_amdgcn_mfma_f32_16x16x32_bf16(ax[ks], bw, acc, 0, 0, 0);
      short8 bn = *(const short8*)&wnb[rowB + ks * 32 + q * 8];
      acc = __builtin_amdgcn_mfma_f32_16x16x32_bf16(aa[ks], bn, acc, 0, 0, 0);
    }
    float bias = bself[ob + m];
#pragma unroll
    for (int r = 0; r < 4; ++r) {
      int node = tb + q * 4 + r;
      if (node < N) {
        float v = acc[r] + bias;
        out[(long long)node * 64 + ob + m] = fmaxf(v, 0.f);
      }
    }
  }
}

extern "C" void kernel_launch(void* const* d_in, const int* in_sizes, int n_in,
                              void* d_out, int out_size, void* d_ws, size_t ws_size,
                              hipStream_t stream) {
  const float* x      = (const float*)d_in[0];
  const int*   eidx   = (const int*)d_in[1];
  const float* Wself  = (const float*)d_in[2];
  const float* bself  = (const float*)d_in[3];
  const float* Wneigh = (const float*)d_in[4];
  float* out = (float*)d_out;

  const int N = in_sizes[0] / 64;
  const int E = in_sizes[1] / 2;
  const int* src = eidx;      // edge_index row 0
  const int* dst = eidx + E;  // edge_index row 1
  const int NB = (N + BKN - 1) / BKN;  // 196 buckets of 512 nodes

  // ws layout: xb[N*64] bf16 | aggb[N*64] bf16 | cursor[256] | wsb[4096] bf16
  //            | wnb[4096] bf16 | rowse[N] int2 | ebuf[NB*CAPE] | col[E]
  unsigned short* xb   = (unsigned short*)d_ws;
  unsigned short* aggb = xb + (size_t)N * 64;
  int* cursor   = (int*)(aggb + (size_t)N * 64);
  unsigned short* wsb = (unsigned short*)(cursor + NBMAX);
  unsigned short* wnb = wsb + 4096;
  int2* rowse   = (int2*)(wnb + 4096);
  int* ebuf     = (int*)(rowse + N);
  int* col      = ebuf + (size_t)NB * CAPE;

  hipMemsetAsync(cursor, 0, NBMAX * sizeof(int), stream);

  long long nx = (long long)N * 64;
  const int SCB = (E + CHUNK - 1) / CHUNK;       // 153 scatter blocks
  int xbl = (int)((nx / 8 + 255) / 256);         // 3125 x2bf blocks
  k1_prep<<<SCB + xbl + 1, 256, 0, stream>>>(x, xb, nx, Wself, Wneigh, wsb, wnb,
                                             src, dst, cursor, ebuf, E, NB, SCB);
  sb_csr<<<NB, BKN, 0, stream>>>(cursor, ebuf, col, rowse, N);
  gcn_gather<<<(int)((nx + 255) / 256), 256, 0, stream>>>(xb, rowse, col, aggb, N);
  gcn_gemm<<<(N + 63) / 64, 256, 0, stream>>>(xb, aggb, wsb, bself, wnb, out, N);
}

// Round 3
// 163.027 us; speedup vs baseline: 1.1651x; 1.0357x over previous
//
#include <hip/hip_runtime.h>

// GCN layer: out = relu(x @ W_self^T + b_self + segment_mean(x[src], dst) @ W_neigh^T)
// N = 100000 nodes, D = 64, E = 1.25M edges.
//
// KEY RESTRUCTURE (this round): mean-then-matmul == matmul-then-mean (linearity).
// We compute y = x@Ws^T + b (fp32) and z = x@Wn^T (bf16) FIRST, then the edge
// gather averages z rows and finishes out = relu(y + mean) directly. This
// deletes the xb plane, the aggb intermediate, and the whole trailing GEMM
// launch (two pipeline stages + ~25 MB of intermediate traffic).
//
// Pipeline (memset + 3 kernels):
//   memset      : cursor[256] = 0 (1 KB, capturable stream op).
//   k1_main     : block-role split.
//                 Blocks [0,SCB): LDS-staged radix scatter of edges into 196
//                 buckets of 512 dst-nodes (contiguous-run claim via global
//                 cursor atomics, full-line ebuf writes). CHUNK=4096 (EPT=16;
//                 R2's EPT=32 doubled register staging for no measured gain).
//                 Blocks [SCB,SCB+GB): dual-output MFMA GEMM straight from
//                 fp32 x: y=x@Ws^T+b (fp32, kept full precision), z=x@Wn^T
//                 (bf16). Streaming/MFMA role overlaps the atomic role.
//   sb_csr      : one 512-thread block per bucket (196 blocks). Window read
//                 ONCE into registers, in-LDS node-sort, coalesced flush.
//                 NOTE: LDS *int* atomics only — LDS fp32 atomicAdd is a CAS
//                 loop on gfx950 and serializes (r3/r11: ~500 µs disasters).
//   gather_final: one wave per node on bf16 z rows (128B): 8 edges per
//                 dwordx4, 2 loads in flight, fp32 accumulate, cross-oct
//                 shuffle reduce; epilogue reads y row, out=relu(y+mean).

#define BKSH 9                // log2(nodes per bucket)
#define BKN 512               // nodes per bucket
#define NBMAX 256             // >= NB = 196
#define CAPE 7168             // edge capacity per bucket (mean 6400, +9.6 sigma)
#define WPT (CAPE / BKN)      // window entries per thread in sb_csr = 14
#define CHUNK 4096            // edges per scatter block
#define EPT (CHUNK / 256)     // edges per thread in scatter = 16

typedef __attribute__((ext_vector_type(8))) short short8;
typedef __attribute__((ext_vector_type(4))) float floatx4;

// fp32 -> bf16 round-to-nearest-even, branch-free.
static __device__ inline unsigned short f2bf(float f) {
  union { float f; unsigned int u; } v;
  v.f = f;
  unsigned int r = v.u + 0x7FFFu + ((v.u >> 16) & 1u);
  return (unsigned short)(r >> 16);
}

static __device__ inline short8 pack8(float4 a, float4 b) {
  short8 s;
  s[0] = (short)f2bf(a.x); s[1] = (short)f2bf(a.y);
  s[2] = (short)f2bf(a.z); s[3] = (short)f2bf(a.w);
  s[4] = (short)f2bf(b.x); s[5] = (short)f2bf(b.y);
  s[6] = (short)f2bf(b.z); s[7] = (short)f2bf(b.w);
  return s;
}

// unpack 8 bf16 (4 dwords) and accumulate into 8 fp32.
static __device__ inline void add8(float* a, short8 sv) {
  union { short8 s; unsigned int u[4]; } c; c.s = sv;
#pragma unroll
  for (int i = 0; i < 4; ++i) {
    a[2 * i]     += __uint_as_float(c.u[i] << 16);
    a[2 * i + 1] += __uint_as_float(c.u[i] & 0xFFFF0000u);
  }
}

// Fused: edge radix-scatter (blocks < SCB) | dual-GEMM y,z from fp32 x.
__global__ __launch_bounds__(256) void k1_main(
    const float* __restrict__ x,
    const float* __restrict__ Wself, const float* __restrict__ bself,
    const float* __restrict__ Wneigh,
    float* __restrict__ yb, unsigned short* __restrict__ zb,
    const int* __restrict__ src, const int* __restrict__ dst,
    int* __restrict__ cursor, int* __restrict__ ebuf,
    int E, int N, int NB, int SCB) {
  __shared__ int h[NBMAX], loff[NBMAX], gbase[NBMAX];
  __shared__ int sbuf[CHUNK];
  int t = threadIdx.x;
  int bid = blockIdx.x;

  if (bid >= SCB) {
    // ---- GEMM role: y = x@Ws^T + b (fp32), z = x@Wn^T (bf16) ----
    int lane = t & 63;
    int w = t >> 6;
    int tb = (bid - SCB) * 64 + w * 16;
    int m = lane & 15, q = lane >> 4;

    long long rowA = (long long)min(tb + m, N - 1) * 64;
    short8 ax[2];
#pragma unroll
    for (int ks = 0; ks < 2; ++ks) {
      const float* xr = &x[rowA + ks * 32 + q * 8];
      ax[ks] = pack8(*(const float4*)xr, *(const float4*)(xr + 4));
    }

#pragma unroll
    for (int nt = 0; nt < 4; ++nt) {
      int ob = nt * 16;
      long long rowB = (long long)(ob + m) * 64;
      floatx4 accs = {0.f, 0.f, 0.f, 0.f};
      floatx4 accn = {0.f, 0.f, 0.f, 0.f};
#pragma unroll
      for (int ks = 0; ks < 2; ++ks) {
        const float* pw = &Wself[rowB + ks * 32 + q * 8];
        short8 bs = pack8(*(const float4*)pw, *(const float4*)(pw + 4));
        accs = __builtin_amdgcn_mfma_f32_16x16x32_bf16(ax[ks], bs, accs, 0, 0, 0);
        const float* pn = &Wneigh[rowB + ks * 32 + q * 8];
        short8 bn = pack8(*(const float4*)pn, *(const float4*)(pn + 4));
        accn = __builtin_amdgcn_mfma_f32_16x16x32_bf16(ax[ks], bn, accn, 0, 0, 0);
      }
      float bias = bself[ob + m];
#pragma unroll
      for (int r = 0; r < 4; ++r) {
        int node = tb + q * 4 + r;
        if (node < N) {
          yb[(long long)node * 64 + ob + m] = accs[r] + bias;
          zb[(long long)node * 64 + ob + m] = f2bf(accn[r]);
        }
      }
    }
    return;
  }

  // ---- scatter role ----
  if (t < NBMAX) h[t] = 0;
  __syncthreads();

  int base = bid * CHUNK;
  int myd[EPT], mys[EPT];
#pragma unroll
  for (int i = 0; i < EPT; ++i) {
    int e = base + t + 256 * i;  // coalesced
    if (e < E) {
      myd[i] = dst[e];
      mys[i] = src[e];
      atomicAdd(&h[myd[i] >> BKSH], 1);
    } else myd[i] = -1;
  }
  __syncthreads();

  if (t < 64) {  // wave 0: exclusive scan of h[0..255], 4 per lane
    int i0 = 4 * t;
    int v0 = h[i0], v1 = h[i0 + 1], v2 = h[i0 + 2], v3 = h[i0 + 3];
    int s4 = v0 + v1 + v2 + v3, inc = s4;
#pragma unroll
    for (int off = 1; off < 64; off <<= 1) {
      int u = __shfl_up(inc, off, 64);
      if (t >= off) inc += u;
    }
    int ex = inc - s4;
    loff[i0] = ex; loff[i0 + 1] = ex + v0;
    loff[i0 + 2] = ex + v0 + v1; loff[i0 + 3] = ex + v0 + v1 + v2;
  }
  __syncthreads();

  if (t < NB) {
    if (h[t] > 0) gbase[t] = t * CAPE + atomicAdd(&cursor[t], h[t]);  // claim run
  }
  if (t < NBMAX) h[t] = 0;  // reuse as local cursor
  __syncthreads();

#pragma unroll
  for (int i = 0; i < EPT; ++i) {
    if (myd[i] >= 0) {
      int b = myd[i] >> BKSH;
      int p = atomicAdd(&h[b], 1);           // LDS int atomic: native, fast
      sbuf[loff[b] + p] = mys[i] | ((myd[i] & (BKN - 1)) << 17);  // src < 2^17
    }
  }
  __syncthreads();

  int w = t >> 6, lane = t & 63;
  for (int b = w; b < NB; b += 4) {
    int c = h[b], lo = loff[b], go = gbase[b];
    for (int j = lane; j < c; j += 64)
      ebuf[go + j] = sbuf[lo + j];
  }
}

// One 512-thread block per 512-node bucket (196 blocks). Window read ONCE
// from global into registers; count -> block scan -> in-LDS node-sort ->
// coalesced flush. cnt[] doubles as scatter cursor (seeded with exclusive
// prefix), so the atomicAdd result IS the final sorted position.
__global__ __launch_bounds__(512) void sb_csr(const int* __restrict__ cursor,
                                              const int* __restrict__ ebuf,
                                              int* __restrict__ col,
                                              int2* __restrict__ rowse, int N) {
  __shared__ int sbuf[CAPE];   // 28672 B
  __shared__ int cnt[BKN];     //  2048 B
  __shared__ int wsum[8];      // total ~30.8 KB
  int b = blockIdx.x, t = threadIdx.x;
  int s = b * CAPE;
  int n = cursor[b];
  int e = s + n;

  // stage window into registers (static indices -> stays in VGPRs)
  int my[WPT];
#pragma unroll
  for (int i = 0; i < WPT; ++i) {
    int j = s + t + i * BKN;
    my[i] = (j < e) ? ebuf[j] : -1;  // entries < 2^26, -1 is a safe sentinel
  }

  cnt[t] = 0;
  __syncthreads();
#pragma unroll
  for (int i = 0; i < WPT; ++i)
    if (my[i] >= 0) atomicAdd(&cnt[(my[i] >> 17) & (BKN - 1)], 1);
  __syncthreads();

  // block exclusive scan over 512 (1 per thread, 8 waves)
  int v = cnt[t];
  int lane = t & 63, w = t >> 6;
  int inc = v;
#pragma unroll
  for (int o = 1; o < 64; o <<= 1) {
    int u = __shfl_up(inc, o, 64);
    if (lane >= o) inc += u;
  }
  if (lane == 63) wsum[w] = inc;
  __syncthreads();
  if (t < 8) {
    int s0 = wsum[t], incw = s0;
#pragma unroll
    for (int o = 1; o < 8; o <<= 1) {
      int u = __shfl_up(incw, o, 64);
      if (t >= o) incw += u;
    }
    wsum[t] = incw - s0;
  }
  __syncthreads();
  int ex = wsum[w] + inc - v;
  int node = (b << BKSH) + t;
  if (node < N) rowse[node] = make_int2(s + ex, v);
  __syncthreads();
  cnt[t] = ex;  // seed scatter cursor with exclusive prefix
  __syncthreads();

  // in-LDS node-sort: atomic result is the final position in the window
#pragma unroll
  for (int i = 0; i < WPT; ++i) {
    if (my[i] >= 0) {
      int nl = (my[i] >> 17) & (BKN - 1);
      int p = atomicAdd(&cnt[nl], 1);
      sbuf[p] = my[i] & 0x1FFFF;
    }
  }
  __syncthreads();

  // coalesced flush
  for (int j = t; j < n; j += BKN) col[s + j] = sbuf[j];
}

// One wave per node on bf16 z rows (128B). Oct o handles edges j = s+o,
// s+o+8...; one dwordx4 covers 8 edges (1KB). 2 loads in flight (clamped 2nd
// index hits the same line -> free). fp32 accumulate, 3-round cross-oct
// shuffle reduce; epilogue: out = relu(y + mean) written fp32 (full row
// covered contiguously by 8 lanes x 32B).
__global__ __launch_bounds__(256) void gather_final(
    const unsigned short* __restrict__ zb,
    const int2* __restrict__ rowse,
    const int* __restrict__ col,
    const float* __restrict__ yb,
    float* __restrict__ out, int N) {
  int gid = blockIdx.x * 256 + threadIdx.x;
  int node = gid >> 6;
  if (node >= N) return;
  int lane = threadIdx.x & 63;
  int o = lane >> 3, d = lane & 7;
  int2 se = rowse[node];
  int s = se.x, c = se.y, e = s + c;

  float a[8] = {0.f, 0.f, 0.f, 0.f, 0.f, 0.f, 0.f, 0.f};
  float b2[8] = {0.f, 0.f, 0.f, 0.f, 0.f, 0.f, 0.f, 0.f};
  for (int j = s + o; j < e; j += 16) {
    int c0 = col[j];
    bool h2 = (j + 8) < e;
    int c1 = h2 ? col[j + 8] : c0;  // clamp: redundant load hits same line
    short8 v0 = *(const short8*)&zb[(long long)c0 * 64 + d * 8];
    short8 v1 = *(const short8*)&zb[(long long)c1 * 64 + d * 8];
    add8(a, v0);
    if (h2) add8(b2, v1);
  }
#pragma unroll
  for (int k = 0; k < 8; ++k) a[k] += b2[k];

#pragma unroll
  for (int m = 8; m <= 32; m <<= 1) {
#pragma unroll
    for (int k = 0; k < 8; ++k) a[k] += __shfl_xor(a[k], m, 64);
  }

  if (o == 0) {
    float inv = 1.0f / fmaxf((float)c, 1.0f);
    long long ro = (long long)node * 64 + d * 8;
    float4 y0 = *(const float4*)&yb[ro];
    float4 y1 = *(const float4*)&yb[ro + 4];
    float4 r0, r1;
    r0.x = fmaxf(y0.x + a[0] * inv, 0.f);
    r0.y = fmaxf(y0.y + a[1] * inv, 0.f);
    r0.z = fmaxf(y0.z + a[2] * inv, 0.f);
    r0.w = fmaxf(y0.w + a[3] * inv, 0.f);
    r1.x = fmaxf(y1.x + a[4] * inv, 0.f);
    r1.y = fmaxf(y1.y + a[5] * inv, 0.f);
    r1.z = fmaxf(y1.z + a[6] * inv, 0.f);
    r1.w = fmaxf(y1.w + a[7] * inv, 0.f);
    *(float4*)&out[ro] = r0;
    *(float4*)&out[ro + 4] = r1;
  }
}

extern "C" void kernel_launch(void* const* d_in, const int* in_sizes, int n_in,
                              void* d_out, int out_size, void* d_ws, size_t ws_size,
                              hipStream_t stream) {
  const float* x      = (const float*)d_in[0];
  const int*   eidx   = (const int*)d_in[1];
  const float* Wself  = (const float*)d_in[2];
  const float* bself  = (const float*)d_in[3];
  const float* Wneigh = (const float*)d_in[4];
  float* out = (float*)d_out;

  const int N = in_sizes[0] / 64;
  const int E = in_sizes[1] / 2;
  const int* src = eidx;      // edge_index row 0
  const int* dst = eidx + E;  // edge_index row 1
  const int NB = (N + BKN - 1) / BKN;  // 196 buckets of 512 nodes

  // ws layout: yb fp32[N*64] | zb bf16[N*64] | cursor[256] | rowse int2[N]
  //            | ebuf[NB*CAPE] | col[E]   (~51 MB)
  float* yb = (float*)d_ws;
  unsigned short* zb = (unsigned short*)(yb + (size_t)N * 64);
  int* cursor = (int*)(zb + (size_t)N * 64);
  int2* rowse = (int2*)(cursor + NBMAX);
  int* ebuf   = (int*)(rowse + N);
  int* col    = ebuf + (size_t)NB * CAPE;

  hipMemsetAsync(cursor, 0, NBMAX * sizeof(int), stream);

  const int SCB = (E + CHUNK - 1) / CHUNK;  // 306 scatter blocks
  const int GB = (N + 63) / 64;             // 1563 GEMM blocks
  k1_main<<<SCB + GB, 256, 0, stream>>>(x, Wself, bself, Wneigh, yb, zb,
                                        src, dst, cursor, ebuf, E, N, NB, SCB);
  sb_csr<<<NB, BKN, 0, stream>>>(cursor, ebuf, col, rowse, N);
  gather_final<<<(int)(((long long)N * 64 + 255) / 256), 256, 0, stream>>>(
      zb, rowse, col, yb, out, N);
}